// Round 17
// baseline (772.403 us; speedup 1.0000x reference)
//
#include <hip/hip_runtime.h>
#include <hip/hip_bf16.h>
#include <float.h>

#define NN 3072
#define MM 3072
#define DD 64
#define KK 8
#define NPROB 24
#define NBLK 768          // persistent k_sink blocks (512 thr; exactly 3/CU, all co-resident)

constexpr float C_EPS   = 0.0025f;   // blur^2
constexpr int   C_NITER = 30;
constexpr float LOG2E = 1.4426950408889634f;
constexpr float LN2F  = 0.6931471805599453f;
constexpr float L2_SCAL2 = -0.6438561897747247f;   // log2(0.64)

__device__ __forceinline__ float ex2(float x){ return __builtin_amdgcn_exp2f(x); }
__device__ __forceinline__ float lg2(float x){ return __builtin_amdgcn_logf(x); }

// system-scope relaxed ops: die-level coherent LLC, NO cache invalidation.
__device__ __forceinline__ void  sst(float* p, float v){
    __hip_atomic_store(p, v, __ATOMIC_RELAXED, __HIP_MEMORY_SCOPE_SYSTEM);
}
__device__ __forceinline__ float sld(const float* p){
    return __hip_atomic_load((float*)p, __ATOMIC_RELAXED, __HIP_MEMORY_SCOPE_SYSTEM);
}

// workspace layout in 4-byte units
#define U_FILL 0        // 8 floats  (zeroed by memset)
#define U_MAXC 8        // 4 uints   (zeroed)
#define U_CNTX 12       // 8 int
#define U_CNTY 20       // 8 int
#define U_POSX 28       // 8 int
#define U_POSY 36       // 8 int
#define U_OFFX 44       // 9 int
#define U_OFFY 53       // 9 int
#define U_PNX  64       // 24 int
#define U_PNY  88
#define U_PRB  112
#define U_PCB  136
#define U_PRS  160
#define U_PCS  184
#define U_PCOFF 208     // 25 int
#define U_PTOF  233     // 24 int  (C^T offsets; == PCOFF for symmetric xx/yy)
#define U_TOFF  257     // 25 int
#define U_ACCF  288     // 24 float (zeroed in k_offsets)
#define U_ACCG  312     // 24 float
#define U_TPPA  336     // 24 int team sizes
#define U_ASGN  384     // NBLK ints: (p<<16)|sb        -> [384, 1152)
#define U_BAR   1152    // 24 teams x 64 ints: cnt at p*64, gen at p*64+32 -> [1152, 2688)
#define U_XSQ  2688     // 3072 float     <- single memset covers [0, 2688)
#define U_YSQ  5760     // 3072 float
#define U_PRED 8832     // 3072 int
#define U_ROWS 11904    // 3072 int
#define U_COLS 14976    // 3072 int
#define U_FPOT 18048    // 24*3072 float potentials f
#define U_GPOT 91776    // 24*3072 float potentials g (zeroed by memset)
#define U_SUBC 165504   // compact submatrices C, then appended C^T blocks (floats)

// ---------------- kernel 1: merged prep (blocks 0-11: x side, 12-23: y side) -------------
__global__ __launch_bounds__(256) void k_prep(const float* __restrict__ x,
                                              const float* __restrict__ y,
                                              const float* __restrict__ cc,
                                              const int* __restrict__ predt,
                                              float* wf, int* wi) {
    int tid = threadIdx.x;
    if (blockIdx.x < 12) {
        __shared__ __align__(16) float c_s[KK][DD];
        __shared__ float csq_s[KK];
        __shared__ float fpart[KK];
        for (int e = tid; e < KK*DD; e += 256) c_s[e>>6][e&63] = cc[e];
        if (tid < KK) fpart[tid] = 0.f;
        __syncthreads();
        if (tid < KK) { float s=0.f; for (int d=0; d<DD; ++d){ float v=c_s[tid][d]; s+=v*v; } csq_s[tid]=s; }
        __syncthreads();
        int i = blockIdx.x*256 + tid;
        if (i < NN) {
            const float4* xr = (const float4*)(x + (size_t)i*DD);
            float4 xv[16];
            float xs = 0.f;
            #pragma unroll
            for (int q=0;q<16;++q){ xv[q]=xr[q];
                xs += xv[q].x*xv[q].x + xv[q].y*xv[q].y + xv[q].z*xv[q].z + xv[q].w*xv[q].w; }
            float dk[KK];
            #pragma unroll
            for (int k=0;k<KK;++k){
                const float4* cr = (const float4*)(&c_s[k][0]);
                float dot=0.f;
                #pragma unroll
                for (int q=0;q<16;++q){ float4 cv=cr[q];
                    dot += xv[q].x*cv.x + xv[q].y*cv.y + xv[q].z*cv.z + xv[q].w*cv.w; }
                dk[k] = xs + csq_s[k] - 2.f*dot;
            }
            float dmin = dk[0]; int am=0;
            #pragma unroll
            for (int k=1;k<KK;++k){ if (dk[k] < dmin){ dmin=dk[k]; am=k; } }
            float se=0.f; float ek[KK];
            #pragma unroll
            for (int k=0;k<KK;++k){ ek[k] = ex2((dmin-dk[k])*LOG2E); se+=ek[k]; }
            float inv = 1.f/se;
            #pragma unroll
            for (int k=0;k<KK;++k) atomicAdd(&fpart[k], ek[k]*inv);
            wf[U_XSQ + i] = xs;
            wi[U_PRED + i] = am;
            atomicAdd(&wi[U_CNTX + am], 1);
        }
        __syncthreads();
        if (tid < KK) atomicAdd(&wf[U_FILL + tid], fpart[tid]);
    } else {
        int j = (blockIdx.x-12)*256 + tid;
        if (j < MM) {
            const float4* yr = (const float4*)(y + (size_t)j*DD);
            float s=0.f;
            #pragma unroll
            for (int q=0;q<16;++q){ float4 v=yr[q]; s += v.x*v.x+v.y*v.y+v.z*v.z+v.w*v.w; }
            wf[U_YSQ + j] = s;
            atomicAdd(&wi[U_CNTY + predt[j]], 1);
        }
    }
}

// ---------------- kernel 3: tables + team allocation (LDS arrays, parallel ASGN) ---------
__global__ __launch_bounds__(512) void k_offsets(const float* __restrict__ ftarg,
                                                 float* wf, int* wi, float* out) {
    __shared__ int wk_s[NPROB];
    __shared__ int q_s[NPROB];
    __shared__ int cq_s[NPROB+1];
    int tid = threadIdx.x;
    if (tid == 0){
        int offx=0, offy=0;
        wi[U_OFFX]=0; wi[U_OFFY]=0;
        for (int k=0;k<KK;++k){
            offx += wi[U_CNTX+k]; wi[U_OFFX+k+1]=offx;
            offy += wi[U_CNTY+k]; wi[U_OFFY+k+1]=offy;
        }
        int co=0, to=0;
        for (int k=0;k<KK;++k){
            int cx=wi[U_CNTX+k], cy=wi[U_CNTY+k];
            bool val = (cx>0)&&(cy>0);
            for (int t=0;t<3;++t){
                int p=k*3+t;
                int nx = val ? (t==2?cy:cx) : 0;
                int ny = val ? (t==1?cx:cy) : 0;
                wi[U_PNX+p]=nx; wi[U_PNY+p]=ny;
                wi[U_PRB+p] = (t==2)? wi[U_OFFY+k] : wi[U_OFFX+k];
                wi[U_PCB+p] = (t==1)? wi[U_OFFX+k] : wi[U_OFFY+k];
                wi[U_PRS+p] = (t==2)?1:0;
                wi[U_PCS+p] = (t==1)?0:1;
                wi[U_PCOFF+p]=co; co += nx*ny;
                wi[U_TOFF+p]=to; to += ((nx+31)>>5)*((ny+31)>>5);
                wf[U_ACCF+p]=0.f; wf[U_ACCG+p]=0.f;
                wk_s[p] = val ? nx*ny : 0;
            }
        }
        wi[U_PCOFF+NPROB]=co; wi[U_TOFF+NPROB]=to;
        // C^T blocks appended after all C; xx/yy are symmetric so CT == C
        int cto = co;
        for (int p=0;p<NPROB;++p){
            if (p%3 == 0){ wi[U_PTOF+p] = cto; cto += wi[U_PNX+p]*wi[U_PNY+p]; }
            else         { wi[U_PTOF+p] = wi[U_PCOFF+p]; }
        }
        // ---- work-proportional quotas (arrays in LDS) ----
        long long wsum = 0;
        for (int p=0;p<NPROB;++p) wsum += wk_s[p];
        if (wsum == 0){
            for (int p=0;p<NPROB;++p){ q_s[p]=0; wi[U_TPPA+p]=0; }
        } else {
            int tot=0;
            for (int p=0;p<NPROB;++p){
                int q = (wk_s[p]>0) ? (int)(((long long)NBLK*wk_s[p])/wsum) : 0;
                if (wk_s[p]>0 && q<1) q=1;
                q_s[p]=q; tot += q;
            }
            while (tot < NBLK){
                int best=-1; float br=-1.f;
                for (int p=0;p<NPROB;++p) if (wk_s[p]>0){
                    float r = (float)wk_s[p]/(float)q_s[p];
                    if (r>br){br=r;best=p;}
                }
                q_s[best]++; tot++;
            }
            while (tot > NBLK){
                int best=-1; float br=3.4e38f;
                for (int p=0;p<NPROB;++p) if (q_s[p]>1){
                    float r = (float)wk_s[p]/(float)(q_s[p]-1);
                    if (r<br){br=r;best=p;}
                }
                if (best<0) break;
                q_s[best]--; tot--;
            }
            for (int p=0;p<NPROB;++p) wi[U_TPPA+p]=q_s[p];
        }
        // prefix sums of quotas
        int acc2=0;
        for (int p=0;p<NPROB;++p){ cq_s[p]=acc2; acc2 += (wsum==0)?0:q_s[p]; }
        cq_s[NPROB]=acc2;
        float lf=0.f;
        for (int k=0;k<KK;++k){ float fx = wf[U_FILL+k]/(float)NN; float dd = fx - ftarg[k]; lf += dd*dd; }
        out[0] = lf/(float)KK;
    }
    __syncthreads();
    // ---- parallel block->(p,sb) assignment via quota prefix (contiguous teams) ----
    for (int b = tid; b < NBLK; b += 512){
        int p = 0;
        while (p < NPROB && cq_s[p+1] <= b) ++p;
        int v = (p >= NPROB || b >= cq_s[NPROB]) ? (0xFF<<16) : ((p<<16) | (b - cq_s[p]));
        wi[U_ASGN + b] = v;
    }
}

// ---------------- kernel 4: scatter compact index lists ----------------
__global__ __launch_bounds__(256) void k_scatter(const int* __restrict__ predt, int* wi) {
    int b = blockIdx.x;
    if (b < 12) {
        int i = b*256 + threadIdx.x;
        if (i < NN){ int k = wi[U_PRED+i]; int p = atomicAdd(&wi[U_POSX+k],1);
                     wi[U_ROWS + wi[U_OFFX+k] + p] = i; }
    } else {
        int j = (b-12)*256 + threadIdx.x;
        if (j < MM){ int k = predt[j]; int p = atomicAdd(&wi[U_POSY+k],1);
                     wi[U_COLS + wi[U_OFFY+k] + p] = j; }
    }
}

// ---------------- kernel 5: exact max, 128x128 tiles, 8x8/thread strided, tri-skip -------
__global__ __launch_bounds__(256) void k_maxmat(const float* __restrict__ x,
                                                const float* __restrict__ y,
                                                float* wf, int* wi) {
    int z = blockIdx.z;
    if (z && blockIdx.y > blockIdx.x) return;   // xx/yy symmetric: upper triangle suffices
    const float* A = (z==2)? y : x;
    const float* B = (z==0)? y : ((z==1)? x : y);
    int aqo = (z==2)? U_YSQ : U_XSQ;
    int bqo = (z==1)? U_XSQ : U_YSQ;
    __shared__ float la[128][65];
    __shared__ float lb[128][65];
    __shared__ float laq[128], lbq[128];
    __shared__ float wred[4];
    int tid = threadIdx.x;
    int i0 = blockIdx.y*128, j0 = blockIdx.x*128;
    #pragma unroll
    for (int q=0;q<8;++q){
        int idx = tid + q*256;            // 0..2047 : 128 rows x 16 float4
        int r = idx>>4, c4 = (idx&15)<<2;
        float4 va = *(const float4*)(A + (size_t)(i0+r)*DD + c4);
        la[r][c4]=va.x; la[r][c4+1]=va.y; la[r][c4+2]=va.z; la[r][c4+3]=va.w;
        float4 vb = *(const float4*)(B + (size_t)(j0+r)*DD + c4);
        lb[r][c4]=vb.x; lb[r][c4+1]=vb.y; lb[r][c4+2]=vb.z; lb[r][c4+3]=vb.w;
    }
    if (tid < 128) laq[tid] = wf[aqo + i0 + tid];
    else           lbq[tid-128] = wf[bqo + j0 + (tid-128)];
    __syncthreads();
    int tx = tid & 15, ty = tid >> 4;
    float acc[8][8];
    #pragma unroll
    for (int u=0;u<8;++u)
        #pragma unroll
        for (int s=0;s<8;++s) acc[u][s]=0.f;
    for (int d=0; d<DD; ++d){
        float av[8], bv[8];
        #pragma unroll
        for (int u=0;u<8;++u) av[u]=la[ty+16*u][d];
        #pragma unroll
        for (int s=0;s<8;++s) bv[s]=lb[tx+16*s][d];
        #pragma unroll
        for (int u=0;u<8;++u)
            #pragma unroll
            for (int s=0;s<8;++s) acc[u][s] = fmaf(av[u], bv[s], acc[u][s]);
    }
    float m = 0.f;
    #pragma unroll
    for (int u=0;u<8;++u){
        float aq = laq[ty+16*u];
        #pragma unroll
        for (int s=0;s<8;++s){
            float cst = 0.5f*(aq + lbq[tx+16*s]) - acc[u][s];
            m = fmaxf(m, cst);
        }
    }
    #pragma unroll
    for (int o=32;o;o>>=1) m = fmaxf(m, __shfl_xor(m,o));
    int wid = tid>>6;
    if ((tid&63)==0) wred[wid]=m;
    __syncthreads();
    if (tid==0){
        float mm = fmaxf(fmaxf(wred[0],wred[1]),fmaxf(wred[2],wred[3]));
        atomicMax((unsigned int*)&wi[U_MAXC+z], __float_as_uint(mm));
    }
}

// ---------------- kernel 6: gather compact cost submatrices (+ C^T for xy) ---------------
// ys tile stored TRANSPOSED (ys_t[d][col]) -> conflict-free dot-product reads.
__global__ __launch_bounds__(256) void k_gather(const float* __restrict__ x,
                                                const float* __restrict__ y,
                                                float* wf, int* wi) {
    __shared__ float xs_[32][65];
    __shared__ float ys_t[DD][33];
    __shared__ float cs_[32][33];
    __shared__ float rq[32], cq[32];
    __shared__ int toff_s[NPROB+1];
    int tid = threadIdx.x;
    if (tid <= NPROB) toff_s[tid] = wi[U_TOFF+tid];
    __syncthreads();
    int total = toff_s[NPROB];
    for (int tix = blockIdx.x; tix < total; tix += gridDim.x){
        int p = 0;
        while (toff_s[p+1] <= tix) ++p;
        int nx = wi[U_PNX+p], ny = wi[U_PNY+p];
        int tpr = (ny+31)>>5;
        int loc = tix - toff_s[p];
        int i0 = (loc/tpr)<<5, j0 = (loc%tpr)<<5;
        int rbase = wi[U_PRB+p], cbase = wi[U_PCB+p];
        int rs = wi[U_PRS+p], cs = wi[U_PCS+p];
        const float* rsrc = rs? y : x;
        const float* csrc = cs? y : x;
        const int* rlist = wi + (rs? U_COLS : U_ROWS);
        const int* clist = wi + (cs? U_COLS : U_ROWS);
        int rqo = rs? U_YSQ : U_XSQ;
        int cqo = cs? U_YSQ : U_XSQ;
        size_t coff = (size_t)wi[U_PCOFF+p];
        #pragma unroll
        for (int q=0;q<2;++q){
            int idx4 = tid + q*256;      // 0..511
            int r = idx4>>4, c = (idx4&15)<<2;
            if (i0 + r < nx){
                int gi = rlist[rbase + i0 + r];
                float4 v = *(const float4*)(rsrc + (size_t)gi*DD + c);
                xs_[r][c]=v.x; xs_[r][c+1]=v.y; xs_[r][c+2]=v.z; xs_[r][c+3]=v.w;
                if (c==0) rq[r] = wf[rqo + gi];
            }
            if (j0 + r < ny){
                int gj = clist[cbase + j0 + r];
                float4 v = *(const float4*)(csrc + (size_t)gj*DD + c);
                ys_t[c][r]=v.x; ys_t[c+1][r]=v.y; ys_t[c+2][r]=v.z; ys_t[c+3][r]=v.w;
                if (c==0) cq[r] = wf[cqo + gj];
            }
        }
        __syncthreads();
        int r = tid>>3, cb = (tid&7)<<2;
        float cv[4] = {0.f,0.f,0.f,0.f};
        if (i0 + r < nx){
            float acc[4] = {0.f,0.f,0.f,0.f};
            for (int d=0; d<DD; ++d){
                float xv = xs_[r][d];
                #pragma unroll
                for (int q=0;q<4;++q) acc[q] += xv*ys_t[d][cb+q];
            }
            float* dst = wf + U_SUBC + coff + (size_t)(i0+r)*ny + j0;
            #pragma unroll
            for (int q=0;q<4;++q){
                int j = cb+q;
                cv[q] = 0.5f*(rq[r]+cq[j]) - acc[q];
                if (j0 + j < ny) dst[j] = cv[q];
            }
        }
        if (p%3 == 0){
            #pragma unroll
            for (int q=0;q<4;++q) cs_[r][cb+q] = cv[q];
            __syncthreads();
            if (j0 + r < ny){
                float* dT = wf + U_SUBC + (size_t)wi[U_PTOF+p] + (size_t)(j0+r)*nx + i0;
                #pragma unroll
                for (int q=0;q<4;++q){
                    int ii = cb+q;
                    if (i0 + ii < nx) dT[ii] = cs_[ii][r];
                }
            }
        }
        __syncthreads();
    }
}

// ---------------- sinkhorn sweep: exact online LSE; 2 rows in flight (r11/r15 math) ------
#define LD8F(JB, D00,D01,D02,D03,D10,D11,D12,D13, G0,G1,G2,G3) { \
    int ja=(JB)+lane; \
    D00=R0[ja]; D01=R0[ja+64]; D02=R0[ja+128]; D03=R0[ja+192]; \
    D10=R1[ja]; D11=R1[ja+64]; D12=R1[ja+128]; D13=R1[ja+192]; \
    G0=gs[ja];  G1=gs[ja+64];  G2=gs[ja+128];  G3=gs[ja+192]; }

#define PROCF(D0,D1,D2,D3, G0,G1,G2,G3, M, S) { \
    float t0=fmaf(D0,nie2,G0), t1=fmaf(D1,nie2,G1), t2=fmaf(D2,nie2,G2), t3=fmaf(D3,nie2,G3); \
    float cm = fmaxf(fmaxf(t0,t1),fmaxf(t2,t3)); \
    float mn = fmaxf(M, cm); \
    float sm = ex2(t0-mn) + ex2(t1-mn) + ex2(t2-mn) + ex2(t3-mn); \
    S = fmaf(S, ex2(M-mn), sm); \
    M = mn; }

#define LD8C(JB, D00,D01,D02,D03,D10,D11,D12,D13, G0,G1,G2,G3) { \
    int ja=(JB)+lane, jb_=(JB)+lane+64, jc=(JB)+lane+128, jd=(JB)+lane+192; \
    D00 = (ja <ncols)? R0[ja]  : 0.f;  D01 = (jb_<ncols)? R0[jb_] : 0.f; \
    D02 = (jc <ncols)? R0[jc]  : 0.f;  D03 = (jd <ncols)? R0[jd]  : 0.f; \
    D10 = (ja <ncols)? R1[ja]  : 0.f;  D11 = (jb_<ncols)? R1[jb_] : 0.f; \
    D12 = (jc <ncols)? R1[jc]  : 0.f;  D13 = (jd <ncols)? R1[jd]  : 0.f; \
    G0  = (ja <ncols)? gs[ja]  : 0.f;  G1  = (jb_<ncols)? gs[jb_] : 0.f; \
    G2  = (jc <ncols)? gs[jc]  : 0.f;  G3  = (jd <ncols)? gs[jd]  : 0.f; }

#define PROCR(JB, D0,D1,D2,D3, G0,G1,G2,G3, M, S) { \
    int ja=(JB)+lane, jb_=(JB)+lane+64, jc=(JB)+lane+128, jd=(JB)+lane+192; \
    float t0 = (ja <ncols)? fmaf(D0, nie2, G0) : -3e38f; \
    float t1 = (jb_<ncols)? fmaf(D1, nie2, G1) : -3e38f; \
    float t2 = (jc <ncols)? fmaf(D2, nie2, G2) : -3e38f; \
    float t3 = (jd <ncols)? fmaf(D3, nie2, G3) : -3e38f; \
    float cm = fmaxf(fmaxf(t0,t1),fmaxf(t2,t3)); \
    float mn = fmaxf(M, cm); \
    float sm = ex2(t0-mn) + ex2(t1-mn) + ex2(t2-mn) + ex2(t3-mn); \
    S = fmaf(S, ex2(M-mn), sm); \
    M = mn; }

template<bool FIN>
__device__ __forceinline__ void sweep(const float* __restrict__ Cb, int ldc, int nrows, int ncols,
                                      const float* __restrict__ gs, float* __restrict__ pot,
                                      float ie2, float neL, float l2n, int w, int lane,
                                      float* saccSlot)
{
    float nie2 = -ie2;
    float acc = 0.f;
    int nfull = ncols >> 8;
    int rem   = ncols & 255;
    for (int i0 = w*2; i0 < nrows; i0 += 16){        // 8 waves x 2 rows per pass
        int ia = i0;
        bool v1 = (i0+1 < nrows);
        int ib = v1 ? i0+1 : i0;
        const float* R0 = Cb + (size_t)ia*ldc;
        const float* R1 = Cb + (size_t)ib*ldc;
        float m0=-3e38f, m1=-3e38f, S0=0.f, S1=0.f;
        if (nfull){
            float a00,a01,a02,a03,a10,a11,a12,a13, ga0,ga1,ga2,ga3;
            LD8F(0, a00,a01,a02,a03,a10,a11,a12,a13, ga0,ga1,ga2,ga3)
            for (int v=1; v<nfull; ++v){
                float b00,b01,b02,b03,b10,b11,b12,b13, gb0,gb1,gb2,gb3;
                LD8F(v<<8, b00,b01,b02,b03,b10,b11,b12,b13, gb0,gb1,gb2,gb3)
                PROCF(a00,a01,a02,a03, ga0,ga1,ga2,ga3, m0, S0)
                PROCF(a10,a11,a12,a13, ga0,ga1,ga2,ga3, m1, S1)
                a00=b00; a01=b01; a02=b02; a03=b03;
                a10=b10; a11=b11; a12=b12; a13=b13;
                ga0=gb0; ga1=gb1; ga2=gb2; ga3=gb3;
            }
            PROCF(a00,a01,a02,a03, ga0,ga1,ga2,ga3, m0, S0)
            PROCF(a10,a11,a12,a13, ga0,ga1,ga2,ga3, m1, S1)
        }
        if (rem){
            int jb = nfull<<8;
            float c00,c01,c02,c03,c10,c11,c12,c13, gc0,gc1,gc2,gc3;
            LD8C(jb, c00,c01,c02,c03,c10,c11,c12,c13, gc0,gc1,gc2,gc3)
            PROCR(jb, c00,c01,c02,c03, gc0,gc1,gc2,gc3, m0, S0)
            PROCR(jb, c10,c11,c12,c13, gc0,gc1,gc2,gc3, m1, S1)
        }
        // cross-lane exact LSE merge
        #pragma unroll
        for (int o=32;o;o>>=1){
            float mo=__shfl_xor(m0,o), So=__shfl_xor(S0,o);
            float mn=fmaxf(m0,mo); S0=fmaf(S0,ex2(m0-mn),So*ex2(mo-mn)); m0=mn;
            mo=__shfl_xor(m1,o); So=__shfl_xor(S1,o);
            mn=fmaxf(m1,mo); S1=fmaf(S1,ex2(m1-mn),So*ex2(mo-mn)); m1=mn;
        }
        if (lane==0){
            float v0  = neL*(m0 + lg2(S0) - l2n);
            float v1v = neL*(m1 + lg2(S1) - l2n);
            if (FIN){
                acc += v0;
                if (v1) acc += v1v;
            } else {
                sst(&pot[ia], v0);
                if (v1) sst(&pot[ib], v1v);
            }
        }
    }
    if (FIN && lane==0 && acc != 0.f) atomicAdd(saccSlot, acc);
}

// ---------------- per-team barrier: RELAXED atomics only (proven r10-r15) ---------------
__device__ __forceinline__ void tbar(int* cnt, int* gen, int tpp){
    __syncthreads();
    if (threadIdx.x == 0){
        asm volatile("s_waitcnt vmcnt(0)" ::: "memory");
        int g0 = __hip_atomic_load(gen, __ATOMIC_RELAXED, __HIP_MEMORY_SCOPE_AGENT);
        int a  = __hip_atomic_fetch_add(cnt, 1, __ATOMIC_RELAXED, __HIP_MEMORY_SCOPE_AGENT);
        if (a == tpp-1){
            __hip_atomic_store(cnt, 0, __ATOMIC_RELAXED, __HIP_MEMORY_SCOPE_AGENT);
            __hip_atomic_fetch_add(gen, 1, __ATOMIC_RELAXED, __HIP_MEMORY_SCOPE_AGENT);
        } else {
            int spins = 0;
            while (__hip_atomic_load(gen, __ATOMIC_RELAXED, __HIP_MEMORY_SCOPE_AGENT) == g0){
                __builtin_amdgcn_s_sleep(2);
                if (++spins > 200000) break;   // failsafe: finite wrong run, never a hang
            }
        }
    }
    __syncthreads();
}

// ---------------- kernel 7: persistent sinkhorn — 768 x 512 (3 blocks/CU, 24 waves/CU) ---
// Finalization folded in: after FIN sweeps + team barrier, sb==0 adds its problem's term.
__global__ __launch_bounds__(512) void k_sink(float* wf, int* wi, float* out) {
    int av = wi[U_ASGN + blockIdx.x];
    int p  = av>>16, sb = av & 0xFFFF;
    if (p >= NPROB) return;
    int nx = wi[U_PNX+p], ny = wi[U_PNY+p];
    if (nx <= 0 || ny <= 0) return;
    int tpp = wi[U_TPPA+p];
    int tid = threadIdx.x, w = tid>>6, lane = tid&63;   // 8 waves
    float eps0 = fmaxf(__uint_as_float((unsigned)wi[U_MAXC + (p%3)]), C_EPS);
    const float* C  = wf + U_SUBC + (size_t)wi[U_PCOFF+p];
    const float* CT = wf + U_SUBC + (size_t)wi[U_PTOF+p];
    float* f = wf + U_FPOT + p*3072;
    float* g = wf + U_GPOT + p*3072;
    float l2ny = lg2((float)ny), l2nx = lg2((float)nx);
    int* cnt = wi + U_BAR + p*64;
    int* gen = cnt + 32;
    int rb0 = (sb*nx)/tpp, re0 = ((sb+1)*nx)/tpp;   // this block's f-rows
    int cb0 = (sb*ny)/tpp, ce0 = ((sb+1)*ny)/tpp;   // this block's g-rows (CT rows)
    __shared__ float gs[3072];

    for (int it=0; it<C_NITER; ++it){
        float eps = fmaxf(eps0*ex2((float)it*L2_SCAL2), C_EPS);
        float ie2 = LOG2E/eps, neL = -eps*LN2F;
        for (int j=tid; j<ny; j+=512) gs[j] = sld(g+j)*ie2;
        __syncthreads();
        sweep<false>(C + (size_t)rb0*ny, ny, re0-rb0, ny, gs, f+rb0, ie2, neL, l2ny, w, lane, nullptr);
        tbar(cnt, gen, tpp);
        for (int i=tid; i<nx; i+=512) gs[i] = sld(f+i)*ie2;
        __syncthreads();
        sweep<false>(CT + (size_t)cb0*nx, nx, ce0-cb0, nx, gs, g+cb0, ie2, neL, l2nx, w, lane, nullptr);
        tbar(cnt, gen, tpp);
    }
    {
        float ie2 = LOG2E/C_EPS, neL = -C_EPS*LN2F;
        for (int j=tid; j<ny; j+=512) gs[j] = sld(g+j)*ie2;
        __syncthreads();
        sweep<true>(C + (size_t)rb0*ny, ny, re0-rb0, ny, gs, nullptr, ie2, neL, l2ny, w, lane, &wf[U_ACCF+p]);
        __syncthreads();
        for (int i=tid; i<nx; i+=512) gs[i] = sld(f+i)*ie2;
        __syncthreads();
        sweep<true>(CT + (size_t)cb0*nx, nx, ce0-cb0, nx, gs, nullptr, ie2, neL, l2nx, w, lane, &wf[U_ACCG+p]);
    }
    // ---- finalize this problem's contribution (replaces k_final launch) ----
    tbar(cnt, gen, tpp);
    if (sb==0 && tid==0){
        float af = sld(&wf[U_ACCF+p]);
        float ag = sld(&wf[U_ACCG+p]);
        float wgt = (p%3==0) ? 1.f : -0.5f;
        atomicAdd(out, wgt*(af/(float)nx + ag/(float)ny));
    }
}

extern "C" void kernel_launch(void* const* d_in, const int* in_sizes, int n_in,
                              void* d_out, int out_size, void* d_ws, size_t ws_size,
                              hipStream_t stream) {
    const float* x     = (const float*)d_in[0];
    const float* y     = (const float*)d_in[1];
    const float* cc    = (const float*)d_in[2];
    const float* ft    = (const float*)d_in[3];
    const int*   predt = (const int*)d_in[4];
    float* out = (float*)d_out;
    float* wf = (float*)d_ws;
    int*   wi = (int*)d_ws;

    hipMemsetAsync(d_ws, 0, 2688*sizeof(int), stream);                    // counters + asgn + barriers
    hipMemsetAsync(wf + U_GPOT, 0, NPROB*3072*sizeof(float), stream);     // g potentials start at 0

    k_prep<<<24, 256, 0, stream>>>(x, y, cc, predt, wf, wi);
    k_offsets<<<1, 512, 0, stream>>>(ft, wf, wi, out);  // tables + parallel team assignment
    k_scatter<<<24, 256, 0, stream>>>(predt, wi);
    k_maxmat<<<dim3(24,24,3), 256, 0, stream>>>(x, y, wf, wi);
    k_gather<<<1024, 256, 0, stream>>>(x, y, wf, wi);

    k_sink<<<NBLK, 512, 0, stream>>>(wf, wi, out);      // persistent; finalization folded in
}

// Round 18
// 605.356 us; speedup vs baseline: 1.2759x; 1.2759x over previous
//
#include <hip/hip_runtime.h>
#include <hip/hip_bf16.h>
#include <float.h>

#define NN 3072
#define MM 3072
#define DD 64
#define KK 8
#define NPROB 24
#define NBLK 480          // persistent k_sink blocks (512 thr each; 2/CU, measured optimum)

constexpr float C_EPS   = 0.0025f;   // blur^2
constexpr int   C_NITER = 30;
constexpr float LOG2E = 1.4426950408889634f;
constexpr float LN2F  = 0.6931471805599453f;
constexpr float L2_SCAL2 = -0.6438561897747247f;   // log2(0.64)

__device__ __forceinline__ float ex2(float x){ return __builtin_amdgcn_exp2f(x); }
__device__ __forceinline__ float lg2(float x){ return __builtin_amdgcn_logf(x); }

// system-scope relaxed ops: die-level coherent LLC, NO cache invalidation.
__device__ __forceinline__ void  sst(float* p, float v){
    __hip_atomic_store(p, v, __ATOMIC_RELAXED, __HIP_MEMORY_SCOPE_SYSTEM);
}
__device__ __forceinline__ float sld(const float* p){
    return __hip_atomic_load((float*)p, __ATOMIC_RELAXED, __HIP_MEMORY_SCOPE_SYSTEM);
}

// workspace layout in 4-byte units (r15 layout, proven)
#define U_FILL 0        // 8 floats  (zeroed by memset)
#define U_MAXC 8        // 4 uints   (zeroed)
#define U_CNTX 12       // 8 int
#define U_CNTY 20       // 8 int
#define U_POSX 28       // 8 int
#define U_POSY 36       // 8 int
#define U_OFFX 44       // 9 int
#define U_OFFY 53       // 9 int
#define U_PNX  64       // 24 int
#define U_PNY  88
#define U_PRB  112
#define U_PCB  136
#define U_PRS  160
#define U_PCS  184
#define U_PCOFF 208     // 25 int
#define U_PTOF  233     // 24 int  (C^T offsets; == PCOFF for symmetric xx/yy)
#define U_TOFF  257     // 25 int
#define U_ACCF  288     // 24 float (zeroed in k_offsets)
#define U_ACCG  312     // 24 float
#define U_TPPA  336     // 24 int team sizes
#define U_ASGN  384     // NBLK ints: (p<<16)|sb
#define U_BAR   896     // 24 teams x 64 ints: cnt at p*64, gen at p*64+32 (zeroed)
#define U_XSQ  2432     // 3072 float     <- single memset covers [0, 2432)
#define U_YSQ  5504     // 3072 float
#define U_PRED 8576     // 3072 int
#define U_ROWS 11648    // 3072 int
#define U_COLS 14720    // 3072 int
#define U_FPOT 17792    // 24*3072 float potentials f
#define U_GPOT 91520    // 24*3072 float potentials g (zeroed by memset)
#define U_SUBC 165248   // compact submatrices C, then appended C^T blocks (floats)

// ---------------- kernel 1: merged prep (blocks 0-11: x side, 12-23: y side) -------------
__global__ __launch_bounds__(256) void k_prep(const float* __restrict__ x,
                                              const float* __restrict__ y,
                                              const float* __restrict__ cc,
                                              const int* __restrict__ predt,
                                              float* wf, int* wi) {
    int tid = threadIdx.x;
    if (blockIdx.x < 12) {
        __shared__ __align__(16) float c_s[KK][DD];
        __shared__ float csq_s[KK];
        __shared__ float fpart[KK];
        for (int e = tid; e < KK*DD; e += 256) c_s[e>>6][e&63] = cc[e];
        if (tid < KK) fpart[tid] = 0.f;
        __syncthreads();
        if (tid < KK) { float s=0.f; for (int d=0; d<DD; ++d){ float v=c_s[tid][d]; s+=v*v; } csq_s[tid]=s; }
        __syncthreads();
        int i = blockIdx.x*256 + tid;
        if (i < NN) {
            const float4* xr = (const float4*)(x + (size_t)i*DD);
            float4 xv[16];
            float xs = 0.f;
            #pragma unroll
            for (int q=0;q<16;++q){ xv[q]=xr[q];
                xs += xv[q].x*xv[q].x + xv[q].y*xv[q].y + xv[q].z*xv[q].z + xv[q].w*xv[q].w; }
            float dk[KK];
            #pragma unroll
            for (int k=0;k<KK;++k){
                const float4* cr = (const float4*)(&c_s[k][0]);
                float dot=0.f;
                #pragma unroll
                for (int q=0;q<16;++q){ float4 cv=cr[q];
                    dot += xv[q].x*cv.x + xv[q].y*cv.y + xv[q].z*cv.z + xv[q].w*cv.w; }
                dk[k] = xs + csq_s[k] - 2.f*dot;
            }
            float dmin = dk[0]; int am=0;
            #pragma unroll
            for (int k=1;k<KK;++k){ if (dk[k] < dmin){ dmin=dk[k]; am=k; } }
            float se=0.f; float ek[KK];
            #pragma unroll
            for (int k=0;k<KK;++k){ ek[k] = ex2((dmin-dk[k])*LOG2E); se+=ek[k]; }
            float inv = 1.f/se;
            #pragma unroll
            for (int k=0;k<KK;++k) atomicAdd(&fpart[k], ek[k]*inv);
            wf[U_XSQ + i] = xs;
            wi[U_PRED + i] = am;
            atomicAdd(&wi[U_CNTX + am], 1);
        }
        __syncthreads();
        if (tid < KK) atomicAdd(&wf[U_FILL + tid], fpart[tid]);
    } else {
        int j = (blockIdx.x-12)*256 + tid;
        if (j < MM) {
            const float4* yr = (const float4*)(y + (size_t)j*DD);
            float s=0.f;
            #pragma unroll
            for (int q=0;q<16;++q){ float4 v=yr[q]; s += v.x*v.x+v.y*v.y+v.z*v.z+v.w*v.w; }
            wf[U_YSQ + j] = s;
            atomicAdd(&wi[U_CNTY + predt[j]], 1);
        }
    }
}

// ---------------- kernel 3: tables + team allocation (LDS arrays, parallel ASGN) ---------
__global__ __launch_bounds__(512) void k_offsets(const float* __restrict__ ftarg,
                                                 float* wf, int* wi, float* out) {
    __shared__ int wk_s[NPROB];
    __shared__ int q_s[NPROB];
    __shared__ int cq_s[NPROB+1];
    int tid = threadIdx.x;
    if (tid == 0){
        int offx=0, offy=0;
        wi[U_OFFX]=0; wi[U_OFFY]=0;
        for (int k=0;k<KK;++k){
            offx += wi[U_CNTX+k]; wi[U_OFFX+k+1]=offx;
            offy += wi[U_CNTY+k]; wi[U_OFFY+k+1]=offy;
        }
        int co=0, to=0;
        for (int k=0;k<KK;++k){
            int cx=wi[U_CNTX+k], cy=wi[U_CNTY+k];
            bool val = (cx>0)&&(cy>0);
            for (int t=0;t<3;++t){
                int p=k*3+t;
                int nx = val ? (t==2?cy:cx) : 0;
                int ny = val ? (t==1?cx:cy) : 0;
                wi[U_PNX+p]=nx; wi[U_PNY+p]=ny;
                wi[U_PRB+p] = (t==2)? wi[U_OFFY+k] : wi[U_OFFX+k];
                wi[U_PCB+p] = (t==1)? wi[U_OFFX+k] : wi[U_OFFY+k];
                wi[U_PRS+p] = (t==2)?1:0;
                wi[U_PCS+p] = (t==1)?0:1;
                wi[U_PCOFF+p]=co; co += nx*ny;
                wi[U_TOFF+p]=to; to += ((nx+31)>>5)*((ny+31)>>5);
                wf[U_ACCF+p]=0.f; wf[U_ACCG+p]=0.f;
                wk_s[p] = val ? nx*ny : 0;
            }
        }
        wi[U_PCOFF+NPROB]=co; wi[U_TOFF+NPROB]=to;
        // C^T blocks appended after all C; xx/yy are symmetric so CT == C
        int cto = co;
        for (int p=0;p<NPROB;++p){
            if (p%3 == 0){ wi[U_PTOF+p] = cto; cto += wi[U_PNX+p]*wi[U_PNY+p]; }
            else         { wi[U_PTOF+p] = wi[U_PCOFF+p]; }
        }
        // ---- work-proportional quotas (arrays in LDS) ----
        long long wsum = 0;
        for (int p=0;p<NPROB;++p) wsum += wk_s[p];
        if (wsum == 0){
            for (int p=0;p<NPROB;++p){ q_s[p]=0; wi[U_TPPA+p]=0; }
        } else {
            int tot=0;
            for (int p=0;p<NPROB;++p){
                int q = (wk_s[p]>0) ? (int)(((long long)NBLK*wk_s[p])/wsum) : 0;
                if (wk_s[p]>0 && q<1) q=1;
                q_s[p]=q; tot += q;
            }
            while (tot < NBLK){
                int best=-1; float br=-1.f;
                for (int p=0;p<NPROB;++p) if (wk_s[p]>0){
                    float r = (float)wk_s[p]/(float)q_s[p];
                    if (r>br){br=r;best=p;}
                }
                q_s[best]++; tot++;
            }
            while (tot > NBLK){
                int best=-1; float br=3.4e38f;
                for (int p=0;p<NPROB;++p) if (q_s[p]>1){
                    float r = (float)wk_s[p]/(float)(q_s[p]-1);
                    if (r<br){br=r;best=p;}
                }
                if (best<0) break;
                q_s[best]--; tot--;
            }
            for (int p=0;p<NPROB;++p) wi[U_TPPA+p]=q_s[p];
        }
        // prefix sums of quotas
        int acc2=0;
        for (int p=0;p<NPROB;++p){ cq_s[p]=acc2; acc2 += (wsum==0)?0:q_s[p]; }
        cq_s[NPROB]=acc2;
        float lf=0.f;
        for (int k=0;k<KK;++k){ float fx = wf[U_FILL+k]/(float)NN; float dd = fx - ftarg[k]; lf += dd*dd; }
        out[0] = lf/(float)KK;
    }
    __syncthreads();
    // ---- parallel block->(p,sb) assignment via quota prefix (contiguous teams) ----
    for (int b = tid; b < NBLK; b += 512){
        int p = 0;
        while (p < NPROB && cq_s[p+1] <= b) ++p;
        int v = (p >= NPROB || b >= cq_s[NPROB]) ? (0xFF<<16) : ((p<<16) | (b - cq_s[p]));
        wi[U_ASGN + b] = v;
    }
}

// ---------------- kernel 4: scatter compact index lists ----------------
__global__ __launch_bounds__(256) void k_scatter(const int* __restrict__ predt, int* wi) {
    int b = blockIdx.x;
    if (b < 12) {
        int i = b*256 + threadIdx.x;
        if (i < NN){ int k = wi[U_PRED+i]; int p = atomicAdd(&wi[U_POSX+k],1);
                     wi[U_ROWS + wi[U_OFFX+k] + p] = i; }
    } else {
        int j = (b-12)*256 + threadIdx.x;
        if (j < MM){ int k = predt[j]; int p = atomicAdd(&wi[U_POSY+k],1);
                     wi[U_COLS + wi[U_OFFY+k] + p] = j; }
    }
}

// ---------------- kernel 5: exact max, 128x128 tiles, 8x8/thread strided, tri-skip -------
__global__ __launch_bounds__(256) void k_maxmat(const float* __restrict__ x,
                                                const float* __restrict__ y,
                                                float* wf, int* wi) {
    int z = blockIdx.z;
    if (z && blockIdx.y > blockIdx.x) return;   // xx/yy symmetric: upper triangle suffices
    const float* A = (z==2)? y : x;
    const float* B = (z==0)? y : ((z==1)? x : y);
    int aqo = (z==2)? U_YSQ : U_XSQ;
    int bqo = (z==1)? U_XSQ : U_YSQ;
    __shared__ float la[128][65];
    __shared__ float lb[128][65];
    __shared__ float laq[128], lbq[128];
    __shared__ float wred[4];
    int tid = threadIdx.x;
    int i0 = blockIdx.y*128, j0 = blockIdx.x*128;
    #pragma unroll
    for (int q=0;q<8;++q){
        int idx = tid + q*256;            // 0..2047 : 128 rows x 16 float4
        int r = idx>>4, c4 = (idx&15)<<2;
        float4 va = *(const float4*)(A + (size_t)(i0+r)*DD + c4);
        la[r][c4]=va.x; la[r][c4+1]=va.y; la[r][c4+2]=va.z; la[r][c4+3]=va.w;
        float4 vb = *(const float4*)(B + (size_t)(j0+r)*DD + c4);
        lb[r][c4]=vb.x; lb[r][c4+1]=vb.y; lb[r][c4+2]=vb.z; lb[r][c4+3]=vb.w;
    }
    if (tid < 128) laq[tid] = wf[aqo + i0 + tid];
    else           lbq[tid-128] = wf[bqo + j0 + (tid-128)];
    __syncthreads();
    int tx = tid & 15, ty = tid >> 4;
    float acc[8][8];
    #pragma unroll
    for (int u=0;u<8;++u)
        #pragma unroll
        for (int s=0;s<8;++s) acc[u][s]=0.f;
    for (int d=0; d<DD; ++d){
        float av[8], bv[8];
        #pragma unroll
        for (int u=0;u<8;++u) av[u]=la[ty+16*u][d];
        #pragma unroll
        for (int s=0;s<8;++s) bv[s]=lb[tx+16*s][d];
        #pragma unroll
        for (int u=0;u<8;++u)
            #pragma unroll
            for (int s=0;s<8;++s) acc[u][s] = fmaf(av[u], bv[s], acc[u][s]);
    }
    float m = 0.f;
    #pragma unroll
    for (int u=0;u<8;++u){
        float aq = laq[ty+16*u];
        #pragma unroll
        for (int s=0;s<8;++s){
            float cst = 0.5f*(aq + lbq[tx+16*s]) - acc[u][s];
            m = fmaxf(m, cst);
        }
    }
    #pragma unroll
    for (int o=32;o;o>>=1) m = fmaxf(m, __shfl_xor(m,o));
    int wid = tid>>6;
    if ((tid&63)==0) wred[wid]=m;
    __syncthreads();
    if (tid==0){
        float mm = fmaxf(fmaxf(wred[0],wred[1]),fmaxf(wred[2],wred[3]));
        atomicMax((unsigned int*)&wi[U_MAXC+z], __float_as_uint(mm));
    }
}

// ---------------- kernel 6: gather compact cost submatrices (+ C^T for xy) ---------------
// ys tile stored TRANSPOSED (ys_t[d][col]) -> conflict-free dot-product reads (proven r16).
__global__ __launch_bounds__(256) void k_gather(const float* __restrict__ x,
                                                const float* __restrict__ y,
                                                float* wf, int* wi) {
    __shared__ float xs_[32][65];
    __shared__ float ys_t[DD][33];
    __shared__ float cs_[32][33];
    __shared__ float rq[32], cq[32];
    __shared__ int toff_s[NPROB+1];
    int tid = threadIdx.x;
    if (tid <= NPROB) toff_s[tid] = wi[U_TOFF+tid];
    __syncthreads();
    int total = toff_s[NPROB];
    for (int tix = blockIdx.x; tix < total; tix += gridDim.x){
        int p = 0;
        while (toff_s[p+1] <= tix) ++p;
        int nx = wi[U_PNX+p], ny = wi[U_PNY+p];
        int tpr = (ny+31)>>5;
        int loc = tix - toff_s[p];
        int i0 = (loc/tpr)<<5, j0 = (loc%tpr)<<5;
        int rbase = wi[U_PRB+p], cbase = wi[U_PCB+p];
        int rs = wi[U_PRS+p], cs = wi[U_PCS+p];
        const float* rsrc = rs? y : x;
        const float* csrc = cs? y : x;
        const int* rlist = wi + (rs? U_COLS : U_ROWS);
        const int* clist = wi + (cs? U_COLS : U_ROWS);
        int rqo = rs? U_YSQ : U_XSQ;
        int cqo = cs? U_YSQ : U_XSQ;
        size_t coff = (size_t)wi[U_PCOFF+p];
        #pragma unroll
        for (int q=0;q<2;++q){
            int idx4 = tid + q*256;      // 0..511
            int r = idx4>>4, c = (idx4&15)<<2;
            if (i0 + r < nx){
                int gi = rlist[rbase + i0 + r];
                float4 v = *(const float4*)(rsrc + (size_t)gi*DD + c);
                xs_[r][c]=v.x; xs_[r][c+1]=v.y; xs_[r][c+2]=v.z; xs_[r][c+3]=v.w;
                if (c==0) rq[r] = wf[rqo + gi];
            }
            if (j0 + r < ny){
                int gj = clist[cbase + j0 + r];
                float4 v = *(const float4*)(csrc + (size_t)gj*DD + c);
                ys_t[c][r]=v.x; ys_t[c+1][r]=v.y; ys_t[c+2][r]=v.z; ys_t[c+3][r]=v.w;
                if (c==0) cq[r] = wf[cqo + gj];
            }
        }
        __syncthreads();
        int r = tid>>3, cb = (tid&7)<<2;
        float cv[4] = {0.f,0.f,0.f,0.f};
        if (i0 + r < nx){
            float acc[4] = {0.f,0.f,0.f,0.f};
            for (int d=0; d<DD; ++d){
                float xv = xs_[r][d];
                #pragma unroll
                for (int q=0;q<4;++q) acc[q] += xv*ys_t[d][cb+q];
            }
            float* dst = wf + U_SUBC + coff + (size_t)(i0+r)*ny + j0;
            #pragma unroll
            for (int q=0;q<4;++q){
                int j = cb+q;
                cv[q] = 0.5f*(rq[r]+cq[j]) - acc[q];
                if (j0 + j < ny) dst[j] = cv[q];
            }
        }
        if (p%3 == 0){
            #pragma unroll
            for (int q=0;q<4;++q) cs_[r][cb+q] = cv[q];
            __syncthreads();
            if (j0 + r < ny){
                float* dT = wf + U_SUBC + (size_t)wi[U_PTOF+p] + (size_t)(j0+r)*nx + i0;
                #pragma unroll
                for (int q=0;q<4;++q){
                    int ii = cb+q;
                    if (i0 + ii < nx) dT[ii] = cs_[ii][r];
                }
            }
        }
        __syncthreads();
    }
}

// ---------------- sinkhorn sweep: exact online LSE; 2 rows in flight (r11/r15, measured) --
#define LD8F(JB, D00,D01,D02,D03,D10,D11,D12,D13, G0,G1,G2,G3) { \
    int ja=(JB)+lane; \
    D00=R0[ja]; D01=R0[ja+64]; D02=R0[ja+128]; D03=R0[ja+192]; \
    D10=R1[ja]; D11=R1[ja+64]; D12=R1[ja+128]; D13=R1[ja+192]; \
    G0=gs[ja];  G1=gs[ja+64];  G2=gs[ja+128];  G3=gs[ja+192]; }

#define PROCF(D0,D1,D2,D3, G0,G1,G2,G3, M, S) { \
    float t0=fmaf(D0,nie2,G0), t1=fmaf(D1,nie2,G1), t2=fmaf(D2,nie2,G2), t3=fmaf(D3,nie2,G3); \
    float cm = fmaxf(fmaxf(t0,t1),fmaxf(t2,t3)); \
    float mn = fmaxf(M, cm); \
    float sm = ex2(t0-mn) + ex2(t1-mn) + ex2(t2-mn) + ex2(t3-mn); \
    S = fmaf(S, ex2(M-mn), sm); \
    M = mn; }

#define LD8C(JB, D00,D01,D02,D03,D10,D11,D12,D13, G0,G1,G2,G3) { \
    int ja=(JB)+lane, jb_=(JB)+lane+64, jc=(JB)+lane+128, jd=(JB)+lane+192; \
    D00 = (ja <ncols)? R0[ja]  : 0.f;  D01 = (jb_<ncols)? R0[jb_] : 0.f; \
    D02 = (jc <ncols)? R0[jc]  : 0.f;  D03 = (jd <ncols)? R0[jd]  : 0.f; \
    D10 = (ja <ncols)? R1[ja]  : 0.f;  D11 = (jb_<ncols)? R1[jb_] : 0.f; \
    D12 = (jc <ncols)? R1[jc]  : 0.f;  D13 = (jd <ncols)? R1[jd]  : 0.f; \
    G0  = (ja <ncols)? gs[ja]  : 0.f;  G1  = (jb_<ncols)? gs[jb_] : 0.f; \
    G2  = (jc <ncols)? gs[jc]  : 0.f;  G3  = (jd <ncols)? gs[jd]  : 0.f; }

#define PROCR(JB, D0,D1,D2,D3, G0,G1,G2,G3, M, S) { \
    int ja=(JB)+lane, jb_=(JB)+lane+64, jc=(JB)+lane+128, jd=(JB)+lane+192; \
    float t0 = (ja <ncols)? fmaf(D0, nie2, G0) : -3e38f; \
    float t1 = (jb_<ncols)? fmaf(D1, nie2, G1) : -3e38f; \
    float t2 = (jc <ncols)? fmaf(D2, nie2, G2) : -3e38f; \
    float t3 = (jd <ncols)? fmaf(D3, nie2, G3) : -3e38f; \
    float cm = fmaxf(fmaxf(t0,t1),fmaxf(t2,t3)); \
    float mn = fmaxf(M, cm); \
    float sm = ex2(t0-mn) + ex2(t1-mn) + ex2(t2-mn) + ex2(t3-mn); \
    S = fmaf(S, ex2(M-mn), sm); \
    M = mn; }

template<bool FIN>
__device__ __forceinline__ void sweep(const float* __restrict__ Cb, int ldc, int nrows, int ncols,
                                      const float* __restrict__ gs, float* __restrict__ pot,
                                      float ie2, float neL, float l2n, int w, int lane,
                                      float* saccSlot)
{
    float nie2 = -ie2;
    float acc = 0.f;
    int nfull = ncols >> 8;
    int rem   = ncols & 255;
    for (int i0 = w*2; i0 < nrows; i0 += 16){        // 8 waves x 2 rows per pass
        int ia = i0;
        bool v1 = (i0+1 < nrows);
        int ib = v1 ? i0+1 : i0;
        const float* R0 = Cb + (size_t)ia*ldc;
        const float* R1 = Cb + (size_t)ib*ldc;
        float m0=-3e38f, m1=-3e38f, S0=0.f, S1=0.f;
        if (nfull){
            float a00,a01,a02,a03,a10,a11,a12,a13, ga0,ga1,ga2,ga3;
            LD8F(0, a00,a01,a02,a03,a10,a11,a12,a13, ga0,ga1,ga2,ga3)
            for (int v=1; v<nfull; ++v){
                float b00,b01,b02,b03,b10,b11,b12,b13, gb0,gb1,gb2,gb3;
                LD8F(v<<8, b00,b01,b02,b03,b10,b11,b12,b13, gb0,gb1,gb2,gb3)
                PROCF(a00,a01,a02,a03, ga0,ga1,ga2,ga3, m0, S0)
                PROCF(a10,a11,a12,a13, ga0,ga1,ga2,ga3, m1, S1)
                a00=b00; a01=b01; a02=b02; a03=b03;
                a10=b10; a11=b11; a12=b12; a13=b13;
                ga0=gb0; ga1=gb1; ga2=gb2; ga3=gb3;
            }
            PROCF(a00,a01,a02,a03, ga0,ga1,ga2,ga3, m0, S0)
            PROCF(a10,a11,a12,a13, ga0,ga1,ga2,ga3, m1, S1)
        }
        if (rem){
            int jb = nfull<<8;
            float c00,c01,c02,c03,c10,c11,c12,c13, gc0,gc1,gc2,gc3;
            LD8C(jb, c00,c01,c02,c03,c10,c11,c12,c13, gc0,gc1,gc2,gc3)
            PROCR(jb, c00,c01,c02,c03, gc0,gc1,gc2,gc3, m0, S0)
            PROCR(jb, c10,c11,c12,c13, gc0,gc1,gc2,gc3, m1, S1)
        }
        // cross-lane exact LSE merge
        #pragma unroll
        for (int o=32;o;o>>=1){
            float mo=__shfl_xor(m0,o), So=__shfl_xor(S0,o);
            float mn=fmaxf(m0,mo); S0=fmaf(S0,ex2(m0-mn),So*ex2(mo-mn)); m0=mn;
            mo=__shfl_xor(m1,o); So=__shfl_xor(S1,o);
            mn=fmaxf(m1,mo); S1=fmaf(S1,ex2(m1-mn),So*ex2(mo-mn)); m1=mn;
        }
        if (lane==0){
            float v0  = neL*(m0 + lg2(S0) - l2n);
            float v1v = neL*(m1 + lg2(S1) - l2n);
            if (FIN){
                acc += v0;
                if (v1) acc += v1v;
            } else {
                sst(&pot[ia], v0);
                if (v1) sst(&pot[ib], v1v);
            }
        }
    }
    if (FIN && lane==0 && acc != 0.f) atomicAdd(saccSlot, acc);
}

// ---------------- per-team barrier: RELAXED atomics only (proven r10-r17) ---------------
__device__ __forceinline__ void tbar(int* cnt, int* gen, int tpp){
    __syncthreads();
    if (threadIdx.x == 0){
        asm volatile("s_waitcnt vmcnt(0)" ::: "memory");
        int g0 = __hip_atomic_load(gen, __ATOMIC_RELAXED, __HIP_MEMORY_SCOPE_AGENT);
        int a  = __hip_atomic_fetch_add(cnt, 1, __ATOMIC_RELAXED, __HIP_MEMORY_SCOPE_AGENT);
        if (a == tpp-1){
            __hip_atomic_store(cnt, 0, __ATOMIC_RELAXED, __HIP_MEMORY_SCOPE_AGENT);
            __hip_atomic_fetch_add(gen, 1, __ATOMIC_RELAXED, __HIP_MEMORY_SCOPE_AGENT);
        } else {
            int spins = 0;
            while (__hip_atomic_load(gen, __ATOMIC_RELAXED, __HIP_MEMORY_SCOPE_AGENT) == g0){
                __builtin_amdgcn_s_sleep(2);
                if (++spins > 200000) break;   // failsafe: finite wrong run, never a hang
            }
        }
    }
    __syncthreads();
}

// ---------------- kernel 7: persistent sinkhorn — 480 x 512 (measured optimum) ----------
// Finalization folded in: after FIN sweeps + team barrier, sb==0 adds its problem's term.
__global__ __launch_bounds__(512) void k_sink(float* wf, int* wi, float* out) {
    int av = wi[U_ASGN + blockIdx.x];
    int p  = av>>16, sb = av & 0xFFFF;
    if (p >= NPROB) return;
    int nx = wi[U_PNX+p], ny = wi[U_PNY+p];
    if (nx <= 0 || ny <= 0) return;
    int tpp = wi[U_TPPA+p];
    int tid = threadIdx.x, w = tid>>6, lane = tid&63;   // 8 waves
    float eps0 = fmaxf(__uint_as_float((unsigned)wi[U_MAXC + (p%3)]), C_EPS);
    const float* C  = wf + U_SUBC + (size_t)wi[U_PCOFF+p];
    const float* CT = wf + U_SUBC + (size_t)wi[U_PTOF+p];
    float* f = wf + U_FPOT + p*3072;
    float* g = wf + U_GPOT + p*3072;
    float l2ny = lg2((float)ny), l2nx = lg2((float)nx);
    int* cnt = wi + U_BAR + p*64;
    int* gen = cnt + 32;
    int rb0 = (sb*nx)/tpp, re0 = ((sb+1)*nx)/tpp;   // this block's f-rows
    int cb0 = (sb*ny)/tpp, ce0 = ((sb+1)*ny)/tpp;   // this block's g-rows (CT rows)
    __shared__ float gs[3072];

    for (int it=0; it<C_NITER; ++it){
        float eps = fmaxf(eps0*ex2((float)it*L2_SCAL2), C_EPS);
        float ie2 = LOG2E/eps, neL = -eps*LN2F;
        for (int j=tid; j<ny; j+=512) gs[j] = sld(g+j)*ie2;
        __syncthreads();
        sweep<false>(C + (size_t)rb0*ny, ny, re0-rb0, ny, gs, f+rb0, ie2, neL, l2ny, w, lane, nullptr);
        tbar(cnt, gen, tpp);
        for (int i=tid; i<nx; i+=512) gs[i] = sld(f+i)*ie2;
        __syncthreads();
        sweep<false>(CT + (size_t)cb0*nx, nx, ce0-cb0, nx, gs, g+cb0, ie2, neL, l2nx, w, lane, nullptr);
        tbar(cnt, gen, tpp);
    }
    {
        float ie2 = LOG2E/C_EPS, neL = -C_EPS*LN2F;
        for (int j=tid; j<ny; j+=512) gs[j] = sld(g+j)*ie2;
        __syncthreads();
        sweep<true>(C + (size_t)rb0*ny, ny, re0-rb0, ny, gs, nullptr, ie2, neL, l2ny, w, lane, &wf[U_ACCF+p]);
        __syncthreads();
        for (int i=tid; i<nx; i+=512) gs[i] = sld(f+i)*ie2;
        __syncthreads();
        sweep<true>(CT + (size_t)cb0*nx, nx, ce0-cb0, nx, gs, nullptr, ie2, neL, l2nx, w, lane, &wf[U_ACCG+p]);
    }
    // ---- finalize this problem's contribution (replaces k_final launch; proven r17) ----
    tbar(cnt, gen, tpp);
    if (sb==0 && tid==0){
        float af = sld(&wf[U_ACCF+p]);
        float ag = sld(&wf[U_ACCG+p]);
        float wgt = (p%3==0) ? 1.f : -0.5f;
        atomicAdd(out, wgt*(af/(float)nx + ag/(float)ny));
    }
}

extern "C" void kernel_launch(void* const* d_in, const int* in_sizes, int n_in,
                              void* d_out, int out_size, void* d_ws, size_t ws_size,
                              hipStream_t stream) {
    const float* x     = (const float*)d_in[0];
    const float* y     = (const float*)d_in[1];
    const float* cc    = (const float*)d_in[2];
    const float* ft    = (const float*)d_in[3];
    const int*   predt = (const int*)d_in[4];
    float* out = (float*)d_out;
    float* wf = (float*)d_ws;
    int*   wi = (int*)d_ws;

    hipMemsetAsync(d_ws, 0, 2432*sizeof(int), stream);                    // counters + asgn + barriers
    hipMemsetAsync(wf + U_GPOT, 0, NPROB*3072*sizeof(float), stream);     // g potentials start at 0

    k_prep<<<24, 256, 0, stream>>>(x, y, cc, predt, wf, wi);
    k_offsets<<<1, 512, 0, stream>>>(ft, wf, wi, out);  // tables + parallel team assignment
    k_scatter<<<24, 256, 0, stream>>>(predt, wi);
    k_maxmat<<<dim3(24,24,3), 256, 0, stream>>>(x, y, wf, wi);
    k_gather<<<1024, 256, 0, stream>>>(x, y, wf, wi);

    k_sink<<<NBLK, 512, 0, stream>>>(wf, wi, out);      // persistent; finalization folded in
}